// Round 13
// baseline (264.051 us; speedup 1.0000x reference)
//
#include <hip/hip_runtime.h>
#include <stdint.h>

typedef __attribute__((ext_vector_type(8))) short bf16x8;
typedef __attribute__((ext_vector_type(4))) short bf16x4;
typedef __attribute__((ext_vector_type(4))) float f32x4;
typedef __attribute__((ext_vector_type(16))) float f32x16;
typedef __attribute__((ext_vector_type(4))) unsigned short u16x4;

typedef __attribute__((address_space(3))) unsigned short lds_u16;
typedef const __attribute__((address_space(1))) unsigned short glb_u16;

__device__ __forceinline__ unsigned short f2bf(float f) {
  union { float f; unsigned u; } x; x.f = f;
  unsigned r = x.u + 0x7FFFu + ((x.u >> 16) & 1u);
  return (unsigned short)(r >> 16);
}

// ---------------- fused prep: 3x fp32->bf16 cvt + RoPE tables, one dispatch ----------------
__global__ __launch_bounds__(256) void k_prep(const float* __restrict__ x,
                                              const float* __restrict__ wqkv,
                                              const float* __restrict__ wproj,
                                              unsigned short* __restrict__ xb,
                                              unsigned short* __restrict__ wqkvb,
                                              unsigned short* __restrict__ wprojb,
                                              float* __restrict__ cosT, float* __restrict__ sinT) {
  const int b = blockIdx.x;
  const float* in;
  unsigned short* out;
  int i;
  if (b < 16384) {
    in = x; out = xb; i = b * 256 + threadIdx.x;
  } else if (b < 16384 + 3072) {
    in = wqkv; out = wqkvb; i = (b - 16384) * 256 + threadIdx.x;
  } else if (b < 16384 + 3072 + 1024) {
    in = wproj; out = wprojb; i = (b - 16384 - 3072) * 256 + threadIdx.x;
  } else {
    int n = threadIdx.x;
    int r = n >> 4, cc = n & 15;
    for (int d = 0; d < 64; ++d) {
      int tpos = (d < 32) ? r : cc;
      int j = (d & 31) >> 1;
      float ang = (float)tpos * powf(10000.0f, -(float)j * (1.0f / 16.0f));
      cosT[n * 64 + d] = cosf(ang);
      sinT[n * 64 + d] = sinf(ang);
    }
    return;
  }
  f32x4 v = reinterpret_cast<const f32x4*>(in)[i];
  u16x4 o;
  o[0] = f2bf(v[0]); o[1] = f2bf(v[1]); o[2] = f2bf(v[2]); o[3] = f2bf(v[3]);
  reinterpret_cast<u16x4*>(out)[i] = o;
}

// ============ 256x256xBK64, 8-wave (2x4), pipelined-read phase GEMM ============
// Round-13: MFMA shape 16x16x32 -> 32x32x16 (half the instructions, 25% higher
// per-instr rate, m119). Wave tile 128x64 = 4x2 grid of 32x32 tiles; acc f32x16[4][2].
// A/B frag: row/col = lane&31, k = (lane>>5)*8 + j (symmetric to the validated 16x16
// layout); C/D: col = lane&31, row = (reg&3)+8*(reg>>2)+4*(lane>>5) [m74/m101].
// Read groups and schedule identical to r8 (12/4/8 reads; counted lgkm; vmcnt(8)).
template <int EPI>
__global__ __launch_bounds__(512, 2) void k_gemm(
    const unsigned short* __restrict__ A,  // M x K bf16
    const unsigned short* __restrict__ B,  // N x K bf16 (B^T layout)
    int M, int N, int K, int nTM,
    const float* __restrict__ cosT, const float* __restrict__ sinT,
    unsigned short* __restrict__ qout, unsigned short* __restrict__ kout,
    unsigned short* __restrict__ vTout,
    const float* __restrict__ bias, float* __restrict__ fout) {
  __shared__ unsigned short smem_u16[65536];  // 128 KiB

  const int t = threadIdx.x, w = t >> 6, l = t & 63;
  const int wm = w >> 2, wn = w & 3;
  const int r5 = l & 31, hi5 = l >> 5, x7 = l & 7;

  const int nwg = gridDim.x;
  const int bid = (int)blockIdx.x;
  const int nTN = nwg / nTM;
  const int xcd = bid & 7;
  const int j = bid >> 3;
  const int tn = j % nTN;
  const int tm = xcd * (nTM >> 3) + j / nTN;
  const int m0 = tm * 256, n0 = tn * 256;

  const int rS = t >> 3;
  const int colS = (((t & 7) ^ ((t >> 3) & 7)) * 8);
  const unsigned short* Asrc = A + (size_t)(m0 + rS) * K + colS;
  const unsigned short* Bsrc = B + (size_t)(n0 + rS) * K + colS;
  const size_t hK = (size_t)128 * K;
  const size_t iK = (size_t)64 * K;

#define STG_A(db, half, i, kt)                                                              \
  __builtin_amdgcn_global_load_lds((glb_u16*)(Asrc + (half) * hK + (i) * iK + (kt) * 64),   \
      (lds_u16*)&smem_u16[((db) * 32768 + (half) * 16384 + (i) * 8192 + w * 1024) >> 1],    \
      16, 0, 0)
#define STG_B(db, half, i, kt)                                                                      \
  __builtin_amdgcn_global_load_lds((glb_u16*)(Bsrc + (half) * hK + (i) * iK + (kt) * 64),           \
      (lds_u16*)&smem_u16[(65536 + (db) * 32768 + (half) * 16384 + (i) * 8192 + w * 1024) >> 1],    \
      16, 0, 0)

#pragma unroll
  for (int kk = 0; kk < 2; ++kk) {
    STG_A(kk, 0, 0, kk); STG_A(kk, 0, 1, kk); STG_A(kk, 1, 0, kk); STG_A(kk, 1, 1, kk);
    STG_B(kk, 0, 0, kk); STG_B(kk, 0, 1, kk); STG_B(kk, 1, 0, kk); STG_B(kk, 1, 1, kk);
  }

  f32x16 acc[4][2];
#pragma unroll
  for (int i = 0; i < 4; ++i)
#pragma unroll
    for (int jj = 0; jj < 2; ++jj) acc[i][jj] = 0.0f;

  // fragment reads: LDS rows are linear r256*128B per matrix; within-row 16B slot is
  // XOR-swizzled: physical slot = logical ^ (row&7); our rows have row&7 == l&7.
  int ko32[4];
#pragma unroll
  for (int ks2 = 0; ks2 < 4; ++ks2) ko32[ks2] = ((((ks2 << 1) | hi5) ^ x7) << 4);
  const int rA32 = (wm * 128 + r5) * 128;  // + mt*4096
  const int rB32 = (wn * 64 + r5) * 128;   // + nt*4096

  bf16x8 a0[2][4], a1[2][4], bq[2][4];

#define RD_A0(Abo)                                                                         \
  _Pragma("unroll") for (int mt = 0; mt < 2; ++mt)                                         \
  _Pragma("unroll") for (int ks2 = 0; ks2 < 4; ++ks2)                                      \
    a0[mt][ks2] = *(const bf16x8*)&smem_u16[((Abo) + rA32 + mt * 4096 + ko32[ks2]) >> 1];
#define RD_A1(Abo)                                                                         \
  _Pragma("unroll") for (int mt = 0; mt < 2; ++mt)                                         \
  _Pragma("unroll") for (int ks2 = 0; ks2 < 4; ++ks2)                                      \
    a1[mt][ks2] = *(const bf16x8*)&smem_u16[((Abo) + rA32 + (mt + 2) * 4096 + ko32[ks2]) >> 1];
#define RD_BLO(Bbo)                                                                        \
  _Pragma("unroll") for (int ks2 = 0; ks2 < 4; ++ks2)                                      \
    bq[0][ks2] = *(const bf16x8*)&smem_u16[((Bbo) + rB32 + ko32[ks2]) >> 1];
#define RD_BHI(Bbo)                                                                        \
  _Pragma("unroll") for (int ks2 = 0; ks2 < 4; ++ks2)                                      \
    bq[1][ks2] = *(const bf16x8*)&smem_u16[((Bbo) + rB32 + 4096 + ko32[ks2]) >> 1];
#define MFMA_Q(am, nt, mo)                                                                 \
  __builtin_amdgcn_s_setprio(1);                                                           \
  _Pragma("unroll") for (int mt = 0; mt < 2; ++mt)                                         \
  _Pragma("unroll") for (int ks2 = 0; ks2 < 4; ++ks2)                                      \
      acc[mt + (mo)][nt] =                                                                 \
          __builtin_amdgcn_mfma_f32_32x32x16_bf16(am[mt][ks2], bq[nt][ks2], acc[mt + (mo)][nt], 0, 0, 0); \
  __builtin_amdgcn_s_setprio(0)

  asm volatile("s_waitcnt vmcnt(8)" ::: "memory");
  __builtin_amdgcn_s_barrier();
  asm volatile("" ::: "memory");
  RD_A0(0);
  RD_BLO(65536);

  const int nKT = K >> 6;
  for (int k = 0; k < nKT; ++k) {
    const int db = k & 1;
    const int Abo = db * 32768;
    const int Bbo = 65536 + db * 32768;
    const int nAbo = (db ^ 1) * 32768;
    const int nBbo = 65536 + (db ^ 1) * 32768;
    const int k2 = k + 2;
    const bool st = (k2 < nKT);

    // ---- P1: lgkm(0) [R1 done]; issue R2=b_hi; MFMA Q11
    asm volatile("s_waitcnt lgkmcnt(0)" ::: "memory");
    RD_BHI(Bbo);
    MFMA_Q(a0, 0, 0);
    __builtin_amdgcn_s_barrier();
    asm volatile("" ::: "memory");

    // ---- P2: issue R3=a1; lgkm(8) [R2 done, R3 in flight]; stage A*0; MFMA Q12
    RD_A1(Abo);
    asm volatile("s_waitcnt lgkmcnt(8)" ::: "memory");
    if (st) { STG_A(db, 0, 0, k2); STG_A(db, 1, 0, k2); }
    MFMA_Q(a0, 1, 0);
    __builtin_amdgcn_s_barrier();
    asm volatile("" ::: "memory");

    // ---- P3: lgkm(0) [R3 done]; stage B (all); MFMA Q21
    asm volatile("s_waitcnt lgkmcnt(0)" ::: "memory");
    if (st) { STG_B(db, 0, 0, k2); STG_B(db, 0, 1, k2); STG_B(db, 1, 0, k2); STG_B(db, 1, 1, k2); }
    MFMA_Q(a1, 0, 2);
    __builtin_amdgcn_s_barrier();
    asm volatile("" ::: "memory");

    // ---- P4: stage A*1; boundary vmcnt+barrier; issue R1-next; MFMA Q22
    if (st) { STG_A(db, 0, 1, k2); STG_A(db, 1, 1, k2); }
    if (k < nKT - 2) {
      asm volatile("s_waitcnt vmcnt(8)" ::: "memory");
    } else if (k == nKT - 2) {
      asm volatile("s_waitcnt vmcnt(0)" ::: "memory");
    }
    __builtin_amdgcn_s_barrier();
    asm volatile("" ::: "memory");
    if (k + 1 < nKT) { RD_A0(nAbo); RD_BLO(nBbo); }
    __builtin_amdgcn_sched_barrier(0);
    MFMA_Q(a1, 1, 2);
    __builtin_amdgcn_s_barrier();
    asm volatile("" ::: "memory");
  }
#undef STG_A
#undef STG_B
#undef RD_A0
#undef RD_A1
#undef RD_BLO
#undef RD_BHI
#undef MFMA_Q

  // Epilogue. 32x32 C/D: col = lane&31, row = (reg&3) + 8*(reg>>2) + 4*(lane>>5).
  if constexpr (EPI == 0) {
    const int which = n0 >> 10;
    unsigned short* qk = (which == 0) ? qout : kout;
#pragma unroll
    for (int nt = 0; nt < 2; ++nt) {
      const int o = n0 + wn * 64 + nt * 32 + r5;
      const int h = (o >> 6) & 15;
      const int d = o & 63;
      if (which < 2) {
        const float sgn = (d & 1) ? 1.0f : -1.0f;
        const float qscale = (which == 0) ? 0.125f : 1.0f;
#pragma unroll
        for (int mt = 0; mt < 4; ++mt) {
          f32x16 v = acc[mt][nt];
#pragma unroll
          for (int rg = 0; rg < 4; ++rg) {
            const int m = m0 + wm * 128 + mt * 32 + rg * 8 + hi5 * 4;
            const int bb = m >> 8;
            const int nb = m & 255;
            float vv[4], pp[4];
#pragma unroll
            for (int jj = 0; jj < 4; ++jj) {
              vv[jj] = v[rg * 4 + jj];
              pp[jj] = __shfl_xor(vv[jj], 1);
            }
            size_t base = ((size_t)(bb * 16 + h) * 256 + nb) * 64 + d;
#pragma unroll
            for (int jj = 0; jj < 4; ++jj) {
              const int n = nb + jj;
              const float cv = cosT[n * 64 + d];
              const float sv = sinT[n * 64 + d];
              float ov = (vv[jj] * cv + sgn * pp[jj] * sv) * qscale;
              qk[base + (size_t)jj * 64] = f2bf(ov);
            }
          }
        }
      } else {
#pragma unroll
        for (int mt = 0; mt < 4; ++mt) {
          f32x16 v = acc[mt][nt];
#pragma unroll
          for (int rg = 0; rg < 4; ++rg) {
            const int m = m0 + wm * 128 + mt * 32 + rg * 8 + hi5 * 4;
            const int bb = m >> 8;
            const int nb = m & 255;
            u16x4 pk;
            pk[0] = f2bf(v[rg * 4 + 0]);
            pk[1] = f2bf(v[rg * 4 + 1]);
            pk[2] = f2bf(v[rg * 4 + 2]);
            pk[3] = f2bf(v[rg * 4 + 3]);
            size_t idx = ((size_t)(bb * 16 + h) * 64 + d) * 256 + nb;  // vT[b,h,d,n]
            *reinterpret_cast<u16x4*>(vTout + idx) = pk;
          }
        }
      }
    }
  } else {
#pragma unroll
    for (int nt = 0; nt < 2; ++nt) {
      const int o = n0 + wn * 64 + nt * 32 + r5;
      const float bv = bias[o];
#pragma unroll
      for (int mt = 0; mt < 4; ++mt) {
        f32x16 v = acc[mt][nt];
#pragma unroll
        for (int rg = 0; rg < 4; ++rg) {
          const int m = m0 + wm * 128 + mt * 32 + rg * 8 + hi5 * 4;
#pragma unroll
          for (int jj = 0; jj < 4; ++jj) fout[(size_t)(m + jj) * N + o] = v[rg * 4 + jj] + bv;
        }
      }
    }
  }
}

// ---------------- flash attention: no-max softmax + conflict-free pads (r12 proven) ----------------
__global__ __launch_bounds__(256) void k_attn(const unsigned short* __restrict__ Q,
                                              const unsigned short* __restrict__ Kb,
                                              const unsigned short* __restrict__ VT,
                                              unsigned short* __restrict__ Out) {
  constexpr int LDK = 72, LDP = 72;
  __shared__ unsigned short klds[64 * LDK];
  __shared__ unsigned short plds[4][64 * LDP];
  const int bh = blockIdx.x;
  const int bb = bh >> 4, h = bh & 15;
  const int t = threadIdx.x, w = t >> 6, l = t & 63, c = l & 15, g = l >> 4;
  const unsigned short* qh = Q + (size_t)bh * 256 * 64;
  const unsigned short* kh = Kb + (size_t)bh * 256 * 64;
  const unsigned short* vh = VT + (size_t)bh * 64 * 256;
  const int q0 = w * 64;

  bf16x8 qf[4][2];
#pragma unroll
  for (int nf = 0; nf < 4; ++nf)
#pragma unroll
    for (int ks = 0; ks < 2; ++ks)
      qf[nf][ks] = *reinterpret_cast<const bf16x8*>(qh + (q0 + nf * 16 + c) * 64 + ks * 32 + g * 8);

  f32x4 oacc[4][4];
#pragma unroll
  for (int i = 0; i < 4; ++i)
#pragma unroll
    for (int jj = 0; jj < 4; ++jj) oacc[i][jj] = 0.0f;
  float lr[4] = {0.f, 0.f, 0.f, 0.f};

  for (int ch = 0; ch < 4; ++ch) {
    __syncthreads();
    {
      int row = t >> 3, col = (t & 7) * 8;
#pragma unroll
      for (int rep = 0; rep < 2; ++rep) {
        int r = rep * 32 + row;
        bf16x8 kv = *reinterpret_cast<const bf16x8*>(kh + (ch * 64 + r) * 64 + col);
        *reinterpret_cast<bf16x8*>(&klds[r * LDK + col]) = kv;
      }
    }
    __syncthreads();

    f32x4 s[4][4];
#pragma unroll
    for (int i = 0; i < 4; ++i)
#pragma unroll
      for (int jj = 0; jj < 4; ++jj) s[i][jj] = 0.0f;
#pragma unroll
    for (int ks = 0; ks < 2; ++ks) {
      bf16x8 kf[4];
#pragma unroll
      for (int mf = 0; mf < 4; ++mf)
        kf[mf] = *reinterpret_cast<const bf16x8*>(&klds[(mf * 16 + c) * LDK + ks * 32 + g * 8]);
#pragma unroll
      for (int mf = 0; mf < 4; ++mf)
#pragma unroll
        for (int nf = 0; nf < 4; ++nf)
          s[mf][nf] = __builtin_amdgcn_mfma_f32_16x16x32_bf16(kf[mf], qf[nf][ks], s[mf][nf], 0, 0, 0);
    }

    // no-max softmax: p = exp(s); lr += sum(p)
#pragma unroll
    for (int nf = 0; nf < 4; ++nf) {
      float sum = 0.f;
#pragma unroll
      for (int mf = 0; mf < 4; ++mf)
#pragma unroll
        for (int jj = 0; jj < 4; ++jj) {
          float p = __expf(s[mf][nf][jj]);
          s[mf][nf][jj] = p;
          sum += p;
        }
      sum += __shfl_xor(sum, 16);
      sum += __shfl_xor(sum, 32);
      lr[nf] += sum;
    }

#pragma unroll
    for (int mf = 0; mf < 4; ++mf)
#pragma unroll
      for (int nf = 0; nf < 4; ++nf) {
        bf16x4 pk;
        pk[0] = (short)f2bf(s[mf][nf][0]);
        pk[1] = (short)f2bf(s[mf][nf][1]);
        pk[2] = (short)f2bf(s[mf][nf][2]);
        pk[3] = (short)f2bf(s[mf][nf][3]);
        *reinterpret_cast<bf16x4*>(&plds[w][(nf * 16 + c) * LDP + mf * 16 + g * 4]) = pk;
      }

#pragma unroll
    for (int ks = 0; ks < 2; ++ks) {
      bf16x8 vf[4], pf[4];
#pragma unroll
      for (int mf = 0; mf < 4; ++mf)
        vf[mf] = *reinterpret_cast<const bf16x8*>(vh + (mf * 16 + c) * 256 + ch * 64 + ks * 32 + g * 8);
#pragma unroll
      for (int nf = 0; nf < 4; ++nf)
        pf[nf] = *reinterpret_cast<const bf16x8*>(&plds[w][(nf * 16 + c) * LDP + ks * 32 + g * 8]);
#pragma unroll
      for (int mf = 0; mf < 4; ++mf)
#pragma unroll
        for (int nf = 0; nf < 4; ++nf)
          oacc[mf][nf] = __builtin_amdgcn_mfma_f32_16x16x32_bf16(vf[mf], pf[nf], oacc[mf][nf], 0, 0, 0);
    }
  }

  float linv[4];
#pragma unroll
  for (int nf = 0; nf < 4; ++nf) linv[nf] = 1.0f / lr[nf];
#pragma unroll
  for (int mf = 0; mf < 4; ++mf)
#pragma unroll
    for (int nf = 0; nf < 4; ++nf) {
      f32x4 v = oacc[mf][nf];
      u16x4 pk;
      pk[0] = f2bf(v[0] * linv[nf]);
      pk[1] = f2bf(v[1] * linv[nf]);
      pk[2] = f2bf(v[2] * linv[nf]);
      pk[3] = f2bf(v[3] * linv[nf]);
      size_t row = (size_t)bb * 256 + q0 + nf * 16 + c;
      size_t idx = row * 1024 + (size_t)h * 64 + mf * 16 + g * 4;  // out[b,n, h*64+d]
      *reinterpret_cast<u16x4*>(Out + idx) = pk;
    }
}

extern "C" void kernel_launch(void* const* d_in, const int* in_sizes, int n_in,
                              void* d_out, int out_size, void* d_ws, size_t ws_size,
                              hipStream_t stream) {
  const float* x = (const float*)d_in[0];
  const float* wqkv = (const float*)d_in[1];
  const float* wproj = (const float*)d_in[2];
  const float* bproj = (const float*)d_in[3];

  char* ws = (char*)d_ws;
  unsigned short* xb = (unsigned short*)(ws);                 // 33,554,432 B (reused as attn_out)
  unsigned short* wqkvb = (unsigned short*)(ws + 33554432);   //  6,291,456 B
  unsigned short* wprojb = (unsigned short*)(ws + 39845888);  //  2,097,152 B
  float* cosT = (float*)(ws + 41943040);                      //     65,536 B
  float* sinT = (float*)(ws + 42008576);                      //     65,536 B
  unsigned short* qb = (unsigned short*)(ws + 42074112);      // 33,554,432 B
  unsigned short* kb = (unsigned short*)(ws + 75628544);      // 33,554,432 B
  unsigned short* vtb = (unsigned short*)(ws + 109182976);    // 33,554,432 B -> total 142,737,408 B
  unsigned short* attn_out = xb;

  // fused cvt(x) + cvt(wqkv) + cvt(wproj) + RoPE tables
  k_prep<<<16384 + 3072 + 1024 + 1, 256, 0, stream>>>(x, wqkv, wproj, xb, wqkvb, wprojb,
                                                      cosT, sinT);

  // QKV: M=16384 (64 tiles), N=3072 (12 tiles), K=1024; RoPE epilogue. grid=768 (%8==0)
  k_gemm<0><<<64 * 12, 512, 0, stream>>>(xb, wqkvb, 16384, 3072, 1024, 64,
                                         cosT, sinT, qb, kb, vtb, nullptr, nullptr);
  // attention: one block per (b,h)
  k_attn<<<1024, 256, 0, stream>>>(qb, kb, vtb, attn_out);
  // proj: M=16384 (64 tiles), N=1024 (4 tiles), K=1024, +bias, fp32 out. grid=256 (%8==0)
  k_gemm<1><<<64 * 4, 512, 0, stream>>>(attn_out, wprojb, 16384, 1024, 1024, 64,
                                        nullptr, nullptr, nullptr, nullptr, nullptr,
                                        bproj, (float*)d_out);
}

// Round 14
// 254.407 us; speedup vs baseline: 1.0379x; 1.0379x over previous
//
#include <hip/hip_runtime.h>
#include <stdint.h>

typedef __attribute__((ext_vector_type(8))) short bf16x8;
typedef __attribute__((ext_vector_type(4))) short bf16x4;
typedef __attribute__((ext_vector_type(4))) float f32x4;
typedef __attribute__((ext_vector_type(4))) unsigned short u16x4;

typedef __attribute__((address_space(3))) unsigned short lds_u16;
typedef const __attribute__((address_space(1))) unsigned short glb_u16;

__device__ __forceinline__ unsigned short f2bf(float f) {
  union { float f; unsigned u; } x; x.f = f;
  unsigned r = x.u + 0x7FFFu + ((x.u >> 16) & 1u);
  return (unsigned short)(r >> 16);
}

// ---------------- fused prep: 3x fp32->bf16 cvt + RoPE tables, one dispatch ----------------
__global__ __launch_bounds__(256) void k_prep(const float* __restrict__ x,
                                              const float* __restrict__ wqkv,
                                              const float* __restrict__ wproj,
                                              unsigned short* __restrict__ xb,
                                              unsigned short* __restrict__ wqkvb,
                                              unsigned short* __restrict__ wprojb,
                                              float* __restrict__ cosT, float* __restrict__ sinT) {
  const int b = blockIdx.x;
  const float* in;
  unsigned short* out;
  int i;
  if (b < 16384) {
    in = x; out = xb; i = b * 256 + threadIdx.x;
  } else if (b < 16384 + 3072) {
    in = wqkv; out = wqkvb; i = (b - 16384) * 256 + threadIdx.x;
  } else if (b < 16384 + 3072 + 1024) {
    in = wproj; out = wprojb; i = (b - 16384 - 3072) * 256 + threadIdx.x;
  } else {
    int n = threadIdx.x;
    int r = n >> 4, cc = n & 15;
    for (int d = 0; d < 64; ++d) {
      int tpos = (d < 32) ? r : cc;
      int j = (d & 31) >> 1;
      float ang = (float)tpos * powf(10000.0f, -(float)j * (1.0f / 16.0f));
      cosT[n * 64 + d] = cosf(ang);
      sinT[n * 64 + d] = sinf(ang);
    }
    return;
  }
  f32x4 v = reinterpret_cast<const f32x4*>(in)[i];
  u16x4 o;
  o[0] = f2bf(v[0]); o[1] = f2bf(v[1]); o[2] = f2bf(v[2]); o[3] = f2bf(v[3]);
  reinterpret_cast<u16x4*>(out)[i] = o;
}

// ============ 256x256xBK64, 8-wave (2x4), pipelined-read phase GEMM ============
// (round-8 best-measured version — 16x16x32 MFMA + full-strength row&7 XOR swizzle.
// r13's 32x32x16 variant regressed: 4-way conflicts cost more than halved MFMA count.)
template <int EPI>
__global__ __launch_bounds__(512, 2) void k_gemm(
    const unsigned short* __restrict__ A,  // M x K bf16
    const unsigned short* __restrict__ B,  // N x K bf16 (B^T layout)
    int M, int N, int K, int nTM,
    const float* __restrict__ cosT, const float* __restrict__ sinT,
    unsigned short* __restrict__ qout, unsigned short* __restrict__ kout,
    unsigned short* __restrict__ vTout,
    const float* __restrict__ bias, float* __restrict__ fout) {
  __shared__ unsigned short smem_u16[65536];  // 128 KiB

  const int t = threadIdx.x, w = t >> 6, l = t & 63, c = l & 15, g = l >> 4;
  const int wm = w >> 2, wn = w & 3;

  const int nwg = gridDim.x;
  const int bid = (int)blockIdx.x;
  const int nTN = nwg / nTM;
  const int xcd = bid & 7;
  const int j = bid >> 3;
  const int tn = j % nTN;
  const int tm = xcd * (nTM >> 3) + j / nTN;
  const int m0 = tm * 256, n0 = tn * 256;

  const int rS = t >> 3;
  const int colS = (((t & 7) ^ ((t >> 3) & 7)) * 8);
  const unsigned short* Asrc = A + (size_t)(m0 + rS) * K + colS;
  const unsigned short* Bsrc = B + (size_t)(n0 + rS) * K + colS;
  const size_t hK = (size_t)128 * K;
  const size_t iK = (size_t)64 * K;

#define STG_A(db, half, i, kt)                                                              \
  __builtin_amdgcn_global_load_lds((glb_u16*)(Asrc + (half) * hK + (i) * iK + (kt) * 64),   \
      (lds_u16*)&smem_u16[((db) * 32768 + (half) * 16384 + (i) * 8192 + w * 1024) >> 1],    \
      16, 0, 0)
#define STG_B(db, half, i, kt)                                                                      \
  __builtin_amdgcn_global_load_lds((glb_u16*)(Bsrc + (half) * hK + (i) * iK + (kt) * 64),           \
      (lds_u16*)&smem_u16[(65536 + (db) * 32768 + (half) * 16384 + (i) * 8192 + w * 1024) >> 1],    \
      16, 0, 0)

#pragma unroll
  for (int kk = 0; kk < 2; ++kk) {
    STG_A(kk, 0, 0, kk); STG_A(kk, 0, 1, kk); STG_A(kk, 1, 0, kk); STG_A(kk, 1, 1, kk);
    STG_B(kk, 0, 0, kk); STG_B(kk, 0, 1, kk); STG_B(kk, 1, 0, kk); STG_B(kk, 1, 1, kk);
  }

  f32x4 acc[8][4];
#pragma unroll
  for (int i = 0; i < 8; ++i)
#pragma unroll
    for (int jj = 0; jj < 4; ++jj) acc[i][jj] = 0.0f;

  const int xm7 = (c & 7) << 4;
  const int ko0 = (g * 16) ^ xm7;
  const int ko1 = (g * 16 + 64) ^ xm7;
  const int rAb = (wm * 128 + c) * 128;
  const int rBb = (wn * 64 + c) * 128;

  bf16x8 a0[4][2], a1[4][2], bq[4][2];

#define RD_A0(Abo)                                                                       \
  _Pragma("unroll") for (int mf = 0; mf < 4; ++mf) {                                     \
    a0[mf][0] = *(const bf16x8*)&smem_u16[((Abo) + rAb + mf * 2048 + ko0) >> 1];         \
    a0[mf][1] = *(const bf16x8*)&smem_u16[((Abo) + rAb + mf * 2048 + ko1) >> 1];         \
  }
#define RD_A1(Abo)                                                                       \
  _Pragma("unroll") for (int mf = 0; mf < 4; ++mf) {                                     \
    a1[mf][0] = *(const bf16x8*)&smem_u16[((Abo) + rAb + (mf + 4) * 2048 + ko0) >> 1];   \
    a1[mf][1] = *(const bf16x8*)&smem_u16[((Abo) + rAb + (mf + 4) * 2048 + ko1) >> 1];   \
  }
#define RD_BLO(Bbo)                                                                      \
  _Pragma("unroll") for (int nf = 0; nf < 2; ++nf) {                                     \
    bq[nf][0] = *(const bf16x8*)&smem_u16[((Bbo) + rBb + nf * 2048 + ko0) >> 1];         \
    bq[nf][1] = *(const bf16x8*)&smem_u16[((Bbo) + rBb + nf * 2048 + ko1) >> 1];         \
  }
#define RD_BHI(Bbo)                                                                      \
  _Pragma("unroll") for (int nf = 2; nf < 4; ++nf) {                                     \
    bq[nf][0] = *(const bf16x8*)&smem_u16[((Bbo) + rBb + nf * 2048 + ko0) >> 1];         \
    bq[nf][1] = *(const bf16x8*)&smem_u16[((Bbo) + rBb + nf * 2048 + ko1) >> 1];         \
  }
#define MFMA_Q(am, bl, bh, mo)                                                           \
  __builtin_amdgcn_s_setprio(1);                                                         \
  _Pragma("unroll") for (int mf = 0; mf < 4; ++mf)                                       \
  _Pragma("unroll") for (int nf = (bl); nf < (bh); ++nf)                                 \
  _Pragma("unroll") for (int ks = 0; ks < 2; ++ks)                                       \
      acc[mf + (mo)][nf] =                                                               \
          __builtin_amdgcn_mfma_f32_16x16x32_bf16(am[mf][ks], bq[nf][ks], acc[mf + (mo)][nf], 0, 0, 0); \
  __builtin_amdgcn_s_setprio(0)

  asm volatile("s_waitcnt vmcnt(8)" ::: "memory");
  __builtin_amdgcn_s_barrier();
  asm volatile("" ::: "memory");
  RD_A0(0);
  RD_BLO(65536);

  const int nKT = K >> 6;
  for (int k = 0; k < nKT; ++k) {
    const int db = k & 1;
    const int Abo = db * 32768;
    const int Bbo = 65536 + db * 32768;
    const int nAbo = (db ^ 1) * 32768;
    const int nBbo = 65536 + (db ^ 1) * 32768;
    const int k2 = k + 2;
    const bool st = (k2 < nKT);

    // ---- P1
    asm volatile("s_waitcnt lgkmcnt(0)" ::: "memory");
    RD_BHI(Bbo);
    MFMA_Q(a0, 0, 2, 0);
    __builtin_amdgcn_s_barrier();
    asm volatile("" ::: "memory");

    // ---- P2
    RD_A1(Abo);
    asm volatile("s_waitcnt lgkmcnt(8)" ::: "memory");
    if (st) { STG_A(db, 0, 0, k2); STG_A(db, 1, 0, k2); }
    MFMA_Q(a0, 2, 4, 0);
    __builtin_amdgcn_s_barrier();
    asm volatile("" ::: "memory");

    // ---- P3
    asm volatile("s_waitcnt lgkmcnt(0)" ::: "memory");
    if (st) { STG_B(db, 0, 0, k2); STG_B(db, 0, 1, k2); STG_B(db, 1, 0, k2); STG_B(db, 1, 1, k2); }
    MFMA_Q(a1, 0, 2, 4);
    __builtin_amdgcn_s_barrier();
    asm volatile("" ::: "memory");

    // ---- P4
    if (st) { STG_A(db, 0, 1, k2); STG_A(db, 1, 1, k2); }
    if (k < nKT - 2) {
      asm volatile("s_waitcnt vmcnt(8)" ::: "memory");
    } else if (k == nKT - 2) {
      asm volatile("s_waitcnt vmcnt(0)" ::: "memory");
    }
    __builtin_amdgcn_s_barrier();
    asm volatile("" ::: "memory");
    if (k + 1 < nKT) { RD_A0(nAbo); RD_BLO(nBbo); }
    __builtin_amdgcn_sched_barrier(0);
    MFMA_Q(a1, 2, 4, 4);
    __builtin_amdgcn_s_barrier();
    asm volatile("" ::: "memory");
  }
#undef STG_A
#undef STG_B
#undef RD_A0
#undef RD_A1
#undef RD_BLO
#undef RD_BHI
#undef MFMA_Q

  if constexpr (EPI == 0) {
    const int which = n0 >> 10;
    unsigned short* qk = (which == 0) ? qout : kout;
#pragma unroll
    for (int nf = 0; nf < 4; ++nf) {
      const int o = n0 + wn * 64 + nf * 16 + c;
      const int h = (o >> 6) & 15;
      const int d = o & 63;
      if (which < 2) {
        const float sgn = (d & 1) ? 1.0f : -1.0f;
        const float qscale = (which == 0) ? 0.125f : 1.0f;
#pragma unroll
        for (int mf = 0; mf < 8; ++mf) {
          const int m = m0 + wm * 128 + mf * 16 + g * 4;
          const int bb = m >> 8;
          const int nb = m & 255;
          f32x4 v = acc[mf][nf];
          f32x4 p;
          p[0] = __shfl_xor(v[0], 1);
          p[1] = __shfl_xor(v[1], 1);
          p[2] = __shfl_xor(v[2], 1);
          p[3] = __shfl_xor(v[3], 1);
          size_t base = ((size_t)(bb * 16 + h) * 256 + nb) * 64 + d;
#pragma unroll
          for (int jj = 0; jj < 4; ++jj) {
            const int n = nb + jj;
            const float cv = cosT[n * 64 + d];
            const float sv = sinT[n * 64 + d];
            float ov = (v[jj] * cv + sgn * p[jj] * sv) * qscale;
            qk[base + (size_t)jj * 64] = f2bf(ov);
          }
        }
      } else {
#pragma unroll
        for (int mf = 0; mf < 8; ++mf) {
          const int m = m0 + wm * 128 + mf * 16 + g * 4;
          const int bb = m >> 8;
          const int nb = m & 255;
          f32x4 v = acc[mf][nf];
          u16x4 pk;
          pk[0] = f2bf(v[0]); pk[1] = f2bf(v[1]); pk[2] = f2bf(v[2]); pk[3] = f2bf(v[3]);
          size_t idx = ((size_t)(bb * 16 + h) * 64 + d) * 256 + nb;
          *reinterpret_cast<u16x4*>(vTout + idx) = pk;
        }
      }
    }
  } else {
#pragma unroll
    for (int nf = 0; nf < 4; ++nf) {
      const int o = n0 + wn * 64 + nf * 16 + c;
      const float bv = bias[o];
#pragma unroll
      for (int mf = 0; mf < 8; ++mf) {
        const int m = m0 + wm * 128 + mf * 16 + g * 4;
        f32x4 v = acc[mf][nf];
#pragma unroll
        for (int jj = 0; jj < 4; ++jj) fout[(size_t)(m + jj) * N + o] = v[jj] + bv;
      }
    }
  }
}

// ---------------- flash attention: no-max softmax + conflict-free pads (r12 proven) ----------------
__global__ __launch_bounds__(256) void k_attn(const unsigned short* __restrict__ Q,
                                              const unsigned short* __restrict__ Kb,
                                              const unsigned short* __restrict__ VT,
                                              unsigned short* __restrict__ Out) {
  constexpr int LDK = 72, LDP = 72;
  __shared__ unsigned short klds[64 * LDK];
  __shared__ unsigned short plds[4][64 * LDP];
  const int bh = blockIdx.x;
  const int bb = bh >> 4, h = bh & 15;
  const int t = threadIdx.x, w = t >> 6, l = t & 63, c = l & 15, g = l >> 4;
  const unsigned short* qh = Q + (size_t)bh * 256 * 64;
  const unsigned short* kh = Kb + (size_t)bh * 256 * 64;
  const unsigned short* vh = VT + (size_t)bh * 64 * 256;
  const int q0 = w * 64;

  bf16x8 qf[4][2];
#pragma unroll
  for (int nf = 0; nf < 4; ++nf)
#pragma unroll
    for (int ks = 0; ks < 2; ++ks)
      qf[nf][ks] = *reinterpret_cast<const bf16x8*>(qh + (q0 + nf * 16 + c) * 64 + ks * 32 + g * 8);

  f32x4 oacc[4][4];
#pragma unroll
  for (int i = 0; i < 4; ++i)
#pragma unroll
    for (int jj = 0; jj < 4; ++jj) oacc[i][jj] = 0.0f;
  float lr[4] = {0.f, 0.f, 0.f, 0.f};

  for (int ch = 0; ch < 4; ++ch) {
    __syncthreads();
    {
      int row = t >> 3, col = (t & 7) * 8;
#pragma unroll
      for (int rep = 0; rep < 2; ++rep) {
        int r = rep * 32 + row;
        bf16x8 kv = *reinterpret_cast<const bf16x8*>(kh + (ch * 64 + r) * 64 + col);
        *reinterpret_cast<bf16x8*>(&klds[r * LDK + col]) = kv;
      }
    }
    __syncthreads();

    f32x4 s[4][4];
#pragma unroll
    for (int i = 0; i < 4; ++i)
#pragma unroll
      for (int jj = 0; jj < 4; ++jj) s[i][jj] = 0.0f;
#pragma unroll
    for (int ks = 0; ks < 2; ++ks) {
      bf16x8 kf[4];
#pragma unroll
      for (int mf = 0; mf < 4; ++mf)
        kf[mf] = *reinterpret_cast<const bf16x8*>(&klds[(mf * 16 + c) * LDK + ks * 32 + g * 8]);
#pragma unroll
      for (int mf = 0; mf < 4; ++mf)
#pragma unroll
        for (int nf = 0; nf < 4; ++nf)
          s[mf][nf] = __builtin_amdgcn_mfma_f32_16x16x32_bf16(kf[mf], qf[nf][ks], s[mf][nf], 0, 0, 0);
    }

    // no-max softmax: p = exp(s); lr += sum(p)  (exact: softmax = exp/sum-exp)
#pragma unroll
    for (int nf = 0; nf < 4; ++nf) {
      float sum = 0.f;
#pragma unroll
      for (int mf = 0; mf < 4; ++mf)
#pragma unroll
        for (int jj = 0; jj < 4; ++jj) {
          float p = __expf(s[mf][nf][jj]);
          s[mf][nf][jj] = p;
          sum += p;
        }
      sum += __shfl_xor(sum, 16);
      sum += __shfl_xor(sum, 32);
      lr[nf] += sum;
    }

#pragma unroll
    for (int mf = 0; mf < 4; ++mf)
#pragma unroll
      for (int nf = 0; nf < 4; ++nf) {
        bf16x4 pk;
        pk[0] = (short)f2bf(s[mf][nf][0]);
        pk[1] = (short)f2bf(s[mf][nf][1]);
        pk[2] = (short)f2bf(s[mf][nf][2]);
        pk[3] = (short)f2bf(s[mf][nf][3]);
        *reinterpret_cast<bf16x4*>(&plds[w][(nf * 16 + c) * LDP + mf * 16 + g * 4]) = pk;
      }

#pragma unroll
    for (int ks = 0; ks < 2; ++ks) {
      bf16x8 vf[4], pf[4];
#pragma unroll
      for (int mf = 0; mf < 4; ++mf)
        vf[mf] = *reinterpret_cast<const bf16x8*>(vh + (mf * 16 + c) * 256 + ch * 64 + ks * 32 + g * 8);
#pragma unroll
      for (int nf = 0; nf < 4; ++nf)
        pf[nf] = *reinterpret_cast<const bf16x8*>(&plds[w][(nf * 16 + c) * LDP + ks * 32 + g * 8]);
#pragma unroll
      for (int mf = 0; mf < 4; ++mf)
#pragma unroll
        for (int nf = 0; nf < 4; ++nf)
          oacc[mf][nf] = __builtin_amdgcn_mfma_f32_16x16x32_bf16(vf[mf], pf[nf], oacc[mf][nf], 0, 0, 0);
    }
  }

  float linv[4];
#pragma unroll
  for (int nf = 0; nf < 4; ++nf) linv[nf] = 1.0f / lr[nf];
#pragma unroll
  for (int mf = 0; mf < 4; ++mf)
#pragma unroll
    for (int nf = 0; nf < 4; ++nf) {
      f32x4 v = oacc[mf][nf];
      u16x4 pk;
      pk[0] = f2bf(v[0] * linv[nf]);
      pk[1] = f2bf(v[1] * linv[nf]);
      pk[2] = f2bf(v[2] * linv[nf]);
      pk[3] = f2bf(v[3] * linv[nf]);
      size_t row = (size_t)bb * 256 + q0 + nf * 16 + c;
      size_t idx = row * 1024 + (size_t)h * 64 + mf * 16 + g * 4;  // out[b,n, h*64+d]
      *reinterpret_cast<u16x4*>(Out + idx) = pk;
    }
}

extern "C" void kernel_launch(void* const* d_in, const int* in_sizes, int n_in,
                              void* d_out, int out_size, void* d_ws, size_t ws_size,
                              hipStream_t stream) {
  const float* x = (const float*)d_in[0];
  const float* wqkv = (const float*)d_in[1];
  const float* wproj = (const float*)d_in[2];
  const float* bproj = (const float*)d_in[3];

  char* ws = (char*)d_ws;
  unsigned short* xb = (unsigned short*)(ws);                 // 33,554,432 B (reused as attn_out)
  unsigned short* wqkvb = (unsigned short*)(ws + 33554432);   //  6,291,456 B
  unsigned short* wprojb = (unsigned short*)(ws + 39845888);  //  2,097,152 B
  float* cosT = (float*)(ws + 41943040);                      //     65,536 B
  float* sinT = (float*)(ws + 42008576);                      //     65,536 B
  unsigned short* qb = (unsigned short*)(ws + 42074112);      // 33,554,432 B
  unsigned short* kb = (unsigned short*)(ws + 75628544);      // 33,554,432 B
  unsigned short* vtb = (unsigned short*)(ws + 109182976);    // 33,554,432 B -> total 142,737,408 B
  unsigned short* attn_out = xb;

  // fused cvt(x) + cvt(wqkv) + cvt(wproj) + RoPE tables
  k_prep<<<16384 + 3072 + 1024 + 1, 256, 0, stream>>>(x, wqkv, wproj, xb, wqkvb, wprojb,
                                                      cosT, sinT);

  // QKV: M=16384 (64 tiles), N=3072 (12 tiles), K=1024; RoPE epilogue. grid=768 (%8==0)
  k_gemm<0><<<64 * 12, 512, 0, stream>>>(xb, wqkvb, 16384, 3072, 1024, 64,
                                         cosT, sinT, qb, kb, vtb, nullptr, nullptr);
  // attention: one block per (b,h)
  k_attn<<<1024, 256, 0, stream>>>(qb, kb, vtb, attn_out);
  // proj: M=16384 (64 tiles), N=1024 (4 tiles), K=1024, +bias, fp32 out. grid=256 (%8==0)
  k_gemm<1><<<64 * 4, 512, 0, stream>>>(attn_out, wprojb, 16384, 1024, 1024, 64,
                                        nullptr, nullptr, nullptr, nullptr, nullptr,
                                        bproj, (float*)d_out);
}